// Round 7
// baseline (86.985 us; speedup 1.0000x reference)
//
#include <hip/hip_runtime.h>
#include <math.h>

#define B_ 32
#define T_ 512
#define D_ 256
#define TP_ 514              // padded T: one zero row each side
#define KTOT 768             // 3 taps x 256 channels
#define NSTEP 24             // KTOT / 32
#define TILE_M 32
#define BUFSZ 18432          // A 2KB bf16 + B 16KB bf16
#define NRING 4

typedef __bf16 bf16x8 __attribute__((ext_vector_type(8)));
typedef float  f32x4  __attribute__((ext_vector_type(4)));

__device__ __forceinline__ void gload16(const void* g, void* l) {
    __builtin_amdgcn_global_load_lds(
        (const __attribute__((address_space(1))) unsigned int*)g,
        (__attribute__((address_space(3))) unsigned int*)l, 16, 0, 0);
}

// Ring-4 LDS pipeline, 3 stages in flight (T3/T4 counted vmcnt).
// 256 threads / 4 waves; block computes 32 rows x 256 cols; wave owns 64 cols
// (acc[2][4], 8 MFMA/step).  Per stage: A 32x32 bf16 (2KB, threads 0..127,
// 1 chunk) + B 256x32 bf16 (16KB, 4 chunks/thread).  Waves 0-1 have 5
// loads/stage, waves 2-3 have 4 -> steady-state vmcnt(8) drains stage k for
// both (15-8=7>=5 oldest incl. all of k; 12-8=4 = exactly k).  Tail: 4, 0.
// XOR swizzle slot=(chunk&3)^(row&3) on both gload source and ds_read.
#define GEMM_PIPE(STAGE, COMPUTE)                                       \
    STAGE(0, 0); STAGE(1, 1); STAGE(2, 2);                              \
    _Pragma("unroll")                                                   \
    for (int k = 0; k < NSTEP; ++k) {                                   \
        if (k < NSTEP - 2)                                              \
            asm volatile("s_waitcnt vmcnt(8)" ::: "memory");            \
        else if (k == NSTEP - 2)                                        \
            asm volatile("s_waitcnt vmcnt(4)" ::: "memory");            \
        else                                                            \
            asm volatile("s_waitcnt vmcnt(0)" ::: "memory");            \
        __builtin_amdgcn_s_barrier();                                   \
        if (k + 3 < NSTEP) STAGE(k + 3, (k + 3) & 3);                   \
        COMPUTE(k & 3);                                                 \
    }

// ---------------- conv1: GEMM + bias/ReLU/LayerNorm -> bf16 h1pad ----------
__global__ __launch_bounds__(256) void gemm1_ln_kernel(
    const __bf16* __restrict__ xpad,   // (B, 514, 256)
    const __bf16* __restrict__ bmat,   // (256, 768)
    const float* __restrict__ bias,
    const float* __restrict__ gamma,
    const float* __restrict__ beta,
    __bf16* __restrict__ dst)          // h1pad (B,514,256)
{
    __shared__ __align__(16) unsigned char ring[NRING * BUFSZ];
    __shared__ float part[32 * 4 * 2];
    __shared__ float tot[32 * 2];
    const int tid = threadIdx.x, lane = tid & 63, wid = tid >> 6;
    const int p = lane & 15, q = lane >> 4;
    const int m0 = blockIdx.x * TILE_M;
    const int bb = m0 >> 9, t0 = m0 & 511;
    const __bf16* aBase = xpad + ((size_t)bb * TP_ + t0) * D_;

    f32x4 acc[2][4];
#pragma unroll
    for (int mf = 0; mf < 2; ++mf)
#pragma unroll
        for (int nf = 0; nf < 4; ++nf)
            acc[mf][nf] = (f32x4){0.f, 0.f, 0.f, 0.f};

    auto STAGE = [&](int kstep, int buf) {
        unsigned char* Ab = ring + buf * BUFSZ;
        if (tid < 128) {   // A: 32 rows x 32 bf16 (128 chunks)
            int r = tid >> 2, scb = (tid & 3) ^ (r & 3);
            int k = kstep >> 3, i0 = (kstep & 7) * 32;
            gload16(aBase + (size_t)(r + k) * D_ + i0 + scb * 8, Ab + tid * 16);
        }
#pragma unroll
        for (int pp = 0; pp < 4; ++pp) {   // B: 256 rows x 32 bf16
            int c = pp * 256 + tid;
            int n = c >> 2, scb = (c & 3) ^ (n & 3);
            gload16(bmat + (size_t)n * KTOT + kstep * 32 + scb * 8,
                    Ab + 2048 + c * 16);
        }
    };
    auto COMPUTE = [&](int buf) {
        unsigned char* Ab = ring + buf * BUFSZ;
        unsigned char* Bb = Ab + 2048;
        const int rA = lane & 15;
        const int swz = (q ^ (rA & 3)) * 16;
        bf16x8 a[2], bv[4];
#pragma unroll
        for (int mf = 0; mf < 2; ++mf)
            a[mf] = *(const bf16x8*)(Ab + (mf * 16 + rA) * 64 + swz);
#pragma unroll
        for (int nf = 0; nf < 4; ++nf)
            bv[nf] = *(const bf16x8*)(Bb + (wid * 64 + nf * 16 + rA) * 64 + swz);
#pragma unroll
        for (int mf = 0; mf < 2; ++mf)
#pragma unroll
            for (int nf = 0; nf < 4; ++nf)
                acc[mf][nf] = __builtin_amdgcn_mfma_f32_16x16x32_bf16(
                    a[mf], bv[nf], acc[mf][nf], 0, 0, 0);
    };

    GEMM_PIPE(STAGE, COMPUTE)

    // ---- epilogue: bias+ReLU -> cross-wave LN -> bf16 h1pad ----
    float bcol[4], gcol[4], becol[4];
#pragma unroll
    for (int nf = 0; nf < 4; ++nf) {
        int c = wid * 64 + nf * 16 + p;
        bcol[nf] = bias[c]; gcol[nf] = gamma[c]; becol[nf] = beta[c];
    }
#pragma unroll
    for (int mf = 0; mf < 2; ++mf)
#pragma unroll
        for (int r = 0; r < 4; ++r) {
            float s = 0.f, s2 = 0.f;
#pragma unroll
            for (int nf = 0; nf < 4; ++nf) {
                float y = fmaxf(acc[mf][nf][r] + bcol[nf], 0.f);
                s += y; s2 += y * y;
            }
#pragma unroll
            for (int off = 8; off >= 1; off >>= 1) {
                s += __shfl_xor(s, off); s2 += __shfl_xor(s2, off);
            }
            if (p == 0) {
                int row = mf * 16 + q * 4 + r;
                part[(row * 4 + wid) * 2]     = s;
                part[(row * 4 + wid) * 2 + 1] = s2;
            }
        }
    __syncthreads();
    if (tid < 32) {
        float s = 0.f, s2 = 0.f;
#pragma unroll
        for (int w = 0; w < 4; ++w) {
            s  += part[(tid * 4 + w) * 2];
            s2 += part[(tid * 4 + w) * 2 + 1];
        }
        float m = s * (1.f / 256.f);
        float v = s2 * (1.f / 256.f) - m * m;
        tot[tid * 2]     = m;
        tot[tid * 2 + 1] = rsqrtf(v + 1e-5f);
    }
    __syncthreads();
#pragma unroll
    for (int mf = 0; mf < 2; ++mf)
#pragma unroll
        for (int r = 0; r < 4; ++r) {
            int row = mf * 16 + q * 4 + r;
            float m  = tot[row * 2];
            float rs = tot[row * 2 + 1];
            size_t gb = ((size_t)bb * TP_ + 1 + t0 + row) * D_;
#pragma unroll
            for (int nf = 0; nf < 4; ++nf) {
                int c = wid * 64 + nf * 16 + p;
                float y = fmaxf(acc[mf][nf][r] + bcol[nf], 0.f);
                dst[gb + c] = (__bf16)((y - m) * rs * gcol[nf] + becol[nf]);
            }
        }
}

// ------------- conv2: GEMM + fused LN + (h@wl+bl) -> pred only -------------
__global__ __launch_bounds__(256) void gemm2_pred_kernel(
    const __bf16* __restrict__ h1pad,  // (B, 514, 256)
    const __bf16* __restrict__ bmat,
    const float* __restrict__ bias,
    const float* __restrict__ gamma,
    const float* __restrict__ beta,
    const float* __restrict__ wl,
    const float* __restrict__ bl,
    float* __restrict__ pred)          // (B, T)
{
    __shared__ __align__(16) unsigned char ring[NRING * BUFSZ];
    __shared__ float part[32 * 4 * 4];
    __shared__ float sg[2];
    const int tid = threadIdx.x, lane = tid & 63, wid = tid >> 6;
    const int p = lane & 15, q = lane >> 4;
    const int m0 = blockIdx.x * TILE_M;
    const int bb = m0 >> 9, t0 = m0 & 511;
    if (tid < 64) {   // Sgw = sum g*wl, Sbw = sum be*wl + bl
        f32x4 g  = *(const f32x4*)(gamma + 4 * tid);
        f32x4 be = *(const f32x4*)(beta  + 4 * tid);
        f32x4 w  = *(const f32x4*)(wl    + 4 * tid);
        float a = g[0]*w[0] + g[1]*w[1] + g[2]*w[2] + g[3]*w[3];
        float b = be[0]*w[0] + be[1]*w[1] + be[2]*w[2] + be[3]*w[3];
#pragma unroll
        for (int off = 32; off >= 1; off >>= 1) {
            a += __shfl_xor(a, off); b += __shfl_xor(b, off);
        }
        if (tid == 0) { sg[0] = a; sg[1] = b + bl[0]; }
    }
    const __bf16* aBase = h1pad + ((size_t)bb * TP_ + t0) * D_;

    f32x4 acc[2][4];
#pragma unroll
    for (int mf = 0; mf < 2; ++mf)
#pragma unroll
        for (int nf = 0; nf < 4; ++nf)
            acc[mf][nf] = (f32x4){0.f, 0.f, 0.f, 0.f};

    auto STAGE = [&](int kstep, int buf) {
        unsigned char* Ab = ring + buf * BUFSZ;
        if (tid < 128) {   // A: 32 rows x 32 bf16
            int r = tid >> 2, scb = (tid & 3) ^ (r & 3);
            int k = kstep >> 3, i0 = (kstep & 7) * 32;
            gload16(aBase + (size_t)(r + k) * D_ + i0 + scb * 8, Ab + tid * 16);
        }
#pragma unroll
        for (int pp = 0; pp < 4; ++pp) {  // B: 256 rows x 32 bf16
            int c = pp * 256 + tid;
            int n = c >> 2, scb = (c & 3) ^ (n & 3);
            gload16(bmat + (size_t)n * KTOT + kstep * 32 + scb * 8,
                    Ab + 2048 + c * 16);
        }
    };
    auto COMPUTE = [&](int buf) {
        unsigned char* Ab = ring + buf * BUFSZ;
        unsigned char* Bb = Ab + 2048;
        const int rA = lane & 15;
        const int swz = (q ^ (rA & 3)) * 16;
        bf16x8 a[2], bv[4];
#pragma unroll
        for (int mf = 0; mf < 2; ++mf)
            a[mf] = *(const bf16x8*)(Ab + (mf * 16 + rA) * 64 + swz);
#pragma unroll
        for (int nf = 0; nf < 4; ++nf)
            bv[nf] = *(const bf16x8*)(Bb + (wid * 64 + nf * 16 + rA) * 64 + swz);
#pragma unroll
        for (int mf = 0; mf < 2; ++mf)
#pragma unroll
            for (int nf = 0; nf < 4; ++nf)
                acc[mf][nf] = __builtin_amdgcn_mfma_f32_16x16x32_bf16(
                    a[mf], bv[nf], acc[mf][nf], 0, 0, 0);
    };

    GEMM_PIPE(STAGE, COMPUTE)

    float bcol[4], gwcol[4];
#pragma unroll
    for (int nf = 0; nf < 4; ++nf) {
        int c = wid * 64 + nf * 16 + p;
        bcol[nf]  = bias[c];
        gwcol[nf] = gamma[c] * wl[c];
    }
#pragma unroll
    for (int mf = 0; mf < 2; ++mf)
#pragma unroll
        for (int r = 0; r < 4; ++r) {
            float s = 0.f, s2 = 0.f, s3 = 0.f;
#pragma unroll
            for (int nf = 0; nf < 4; ++nf) {
                float y = fmaxf(acc[mf][nf][r] + bcol[nf], 0.f);
                s += y; s2 += y * y; s3 += y * gwcol[nf];
            }
#pragma unroll
            for (int off = 8; off >= 1; off >>= 1) {
                s  += __shfl_xor(s, off);
                s2 += __shfl_xor(s2, off);
                s3 += __shfl_xor(s3, off);
            }
            if (p == 0) {
                int row = mf * 16 + q * 4 + r;
                part[(row * 4 + wid) * 4]     = s;
                part[(row * 4 + wid) * 4 + 1] = s2;
                part[(row * 4 + wid) * 4 + 2] = s3;
            }
        }
    __syncthreads();
    if (tid < 32) {
        float s = 0.f, s2 = 0.f, s3 = 0.f;
#pragma unroll
        for (int w = 0; w < 4; ++w) {
            s  += part[(tid * 4 + w) * 4];
            s2 += part[(tid * 4 + w) * 4 + 1];
            s3 += part[(tid * 4 + w) * 4 + 2];
        }
        float m  = s * (1.f / 256.f);
        float v  = s2 * (1.f / 256.f) - m * m;
        float rs = rsqrtf(v + 1e-5f);
        pred[bb * T_ + t0 + tid] = rs * (s3 - m * sg[0]) + sg[1];
    }
}

// prep: scan (blocks 0..31) + bf16 xpad + weight transpose + h1pad pad rows.
__global__ __launch_bounds__(512) void prep_kernel(
    const int* __restrict__ td, const float* __restrict__ x,
    const float* __restrict__ w1, const float* __restrict__ w2,
    int* __restrict__ ends, __bf16* __restrict__ xpad,
    __bf16* __restrict__ bm1, __bf16* __restrict__ bm2,
    __bf16* __restrict__ h1pad)
{
    if (blockIdx.x < 32) {   // inclusive cumsum per batch
        __shared__ int s[T_];
        int b = blockIdx.x, t = threadIdx.x;
        s[t] = td[b * T_ + t];
        __syncthreads();
        for (int off = 1; off < T_; off <<= 1) {
            int add = (t >= off) ? s[t - off] : 0;
            __syncthreads();
            s[t] += add;
            __syncthreads();
        }
        ends[b * T_ + t] = s[t];
        return;
    }
    const int NX8 = B_ * TP_ * D_ / 8;   // 526,336
    const int NW8 = D_ * KTOT / 8;       // 24,576 per conv
    const int NZ8 = B_ * 2 * D_ / 8;     // 2,048
    int idx = (blockIdx.x - 32) * 512 + threadIdx.x;
    if (idx < NX8) {
        int e = idx * 8;
        int b = e / (TP_ * D_);
        int rem = e - b * (TP_ * D_);
        int r = rem >> 8, d = rem & 255;
        int t = r - 1;
        bf16x8 o;
        if ((unsigned)t < (unsigned)T_) {
            const float* xp = x + ((size_t)b * T_ + t) * D_ + d;
            f32x4 v0 = *(const f32x4*)xp;
            f32x4 v1 = *(const f32x4*)(xp + 4);
#pragma unroll
            for (int u = 0; u < 4; ++u) { o[u] = (__bf16)v0[u]; o[u+4] = (__bf16)v1[u]; }
        } else {
#pragma unroll
            for (int u = 0; u < 8; ++u) o[u] = (__bf16)0.f;
        }
        *(bf16x8*)(xpad + e) = o;
    } else if (idx < NX8 + 2 * NW8) {
        int j = (idx - NX8) * 8;
        const float* ws = w1;
        __bf16* bm = bm1;
        if (j >= D_ * KTOT) { j -= D_ * KTOT; ws = w2; bm = bm2; }
        int n = j / KTOT;
        int kap = j - n * KTOT;
        int k = kap >> 8, i = kap & 255;
        bf16x8 o;
#pragma unroll
        for (int u = 0; u < 8; ++u)
            o[u] = (__bf16)ws[(n * D_ + i + u) * 3 + k];
        *(bf16x8*)(bm + n * KTOT + kap) = o;
    } else if (idx < NX8 + 2 * NW8 + NZ8) {
        int j = (idx - NX8 - 2 * NW8) * 8;
        int b = j >> 9, qq = (j >> 8) & 1, d = j & 255;
        bf16x8 o;
#pragma unroll
        for (int u = 0; u < 8; ++u) o[u] = (__bf16)0.f;
        *(bf16x8*)(h1pad + ((size_t)b * TP_ + (qq ? TP_ - 1 : 0)) * D_ + d) = o;
    }
}

// out[b,m,:] = x[b, t(m), :] via binary search over ends; zeros past lens[b].
__global__ __launch_bounds__(256) void gather_kernel(
    const float* __restrict__ x, const int* __restrict__ ends,
    float* __restrict__ out, int maxLen)
{
    int tid = threadIdx.x, wd = tid >> 6, lane = tid & 63;
    int idx = blockIdx.x * 4 + wd;
    int b = idx / maxLen, m = idx % maxLen;
    if (b >= B_) return;
    const int* e = &ends[b * T_];
    float4 r = make_float4(0.f, 0.f, 0.f, 0.f);
    if (m < e[T_ - 1]) {
        int lo = 0, hi = T_ - 1;   // first t with ends[t] > m
        while (lo < hi) {
            int mid = (lo + hi) >> 1;
            if (e[mid] > m) hi = mid; else lo = mid + 1;
        }
        r = *(const float4*)(&x[((size_t)b * T_ + lo) * D_ + 4 * lane]);
    }
    *(float4*)(&out[((size_t)b * maxLen + m) * D_ + 4 * lane]) = r;
}

extern "C" void kernel_launch(void* const* d_in, const int* in_sizes, int n_in,
                              void* d_out, int out_size, void* d_ws, size_t ws_size,
                              hipStream_t stream) {
    const float* x   = (const float*)d_in[0];
    const int*   td  = (const int*)d_in[1];
    const float* w1  = (const float*)d_in[2];
    const float* b1  = (const float*)d_in[3];
    const float* g1  = (const float*)d_in[4];
    const float* be1 = (const float*)d_in[5];
    const float* w2  = (const float*)d_in[6];
    const float* b2  = (const float*)d_in[7];
    const float* g2  = (const float*)d_in[8];
    const float* be2 = (const float*)d_in[9];
    const float* wl  = (const float*)d_in[10];
    const float* bl  = (const float*)d_in[11];
    float* outp = (float*)d_out;

    const int BT = B_ * T_;
    const int maxLen = (out_size - BT) / (B_ * D_);
    float* predp = outp + (size_t)B_ * maxLen * D_;

    const size_t SZ_ENDS = 65536;
    const size_t SZ_XPAD = (size_t)B_ * TP_ * D_ * 2;   // 8,421,376
    const size_t SZ_H1   = SZ_XPAD;
    const size_t SZ_BM   = (size_t)D_ * KTOT * 2;       // 393,216
    const size_t need = SZ_ENDS + SZ_XPAD + SZ_H1 + 2 * SZ_BM;

    int* endsp = (int*)d_ws;                             // always in ws (tiny)
    char* base;
    if (ws_size >= need) base = (char*)d_ws + SZ_ENDS;
    else                 base = (char*)d_out;  // consumed before gather overwrites

    __bf16* xpadp  = (__bf16*)(base);
    __bf16* h1padp = (__bf16*)(base + SZ_XPAD);
    __bf16* bm1p   = (__bf16*)(base + SZ_XPAD + SZ_H1);
    __bf16* bm2p   = (__bf16*)(base + SZ_XPAD + SZ_H1 + SZ_BM);

    prep_kernel<<<32 + 1128, 512, 0, stream>>>(td, x, w1, w2, endsp, xpadp,
                                               bm1p, bm2p, h1padp);
    gemm1_ln_kernel<<<BT / TILE_M, 256, 0, stream>>>(xpadp, bm1p, b1, g1, be1, h1padp);
    gemm2_pred_kernel<<<BT / TILE_M, 256, 0, stream>>>(h1padp, bm2p, b2, g2, be2,
                                                       wl, bl, predp);
    gather_kernel<<<(B_ * maxLen + 3) / 4, 256, 0, stream>>>(x, endsp, outp, maxLen);
}

// Round 8
// 83.770 us; speedup vs baseline: 1.0384x; 1.0384x over previous
//
#include <hip/hip_runtime.h>
#include <math.h>

#define B_ 32
#define T_ 512
#define D_ 256
#define TP_ 514              // padded T: one zero row each side
#define KTOT 768             // 3 taps x 256 channels
#define NSTEP 24             // KTOT / 32
#define TILE_M 64            // output rows per block
#define M1 80                // conv1 computed rows (window [t0-8, t0+72))
#define BUFSZ 21504          // A 5KB (80x64B) + B 16KB
#define H1ROWS 66            // h1 rows [t0-1, t0+65)

typedef __bf16 bf16x8 __attribute__((ext_vector_type(8)));
typedef float  f32x4  __attribute__((ext_vector_type(4)));

__device__ __forceinline__ void gload16(const void* g, void* l) {
    __builtin_amdgcn_global_load_lds(
        (const __attribute__((address_space(1))) unsigned int*)g,
        (__attribute__((address_space(3))) unsigned int*)l, 16, 0, 0);
}

// ---------------------------------------------------------------------------
// Fused conv1 -> LN -> conv2 -> LN + (h@wl+bl).  One block = 64 output rows.
// conv1: 80 rows x 256 cols (acc[5][4]) via R4-style ring-3 LDS pipeline
//   (A 80x32 bf16: 256 chunks all threads + 64 chunks wave0; B 256x32).
// h1 (66 rows = [t0-1, t0+65)) stays in LDS, slot-XOR swizzled (slot^(u&7)).
// conv2: 64 rows (acc[4][4]); A read directly from h1 LDS, B2 ring-staged.
// Epilogue folds LN2 + linear: pred = rstd*(S3 - mean*Sgw) + Sbw.
// ---------------------------------------------------------------------------
__global__ __launch_bounds__(256) void fused_conv_kernel(
    const __bf16* __restrict__ xpad,   // (B, 514, 256)
    const __bf16* __restrict__ bm1,    // (256, 768)
    const __bf16* __restrict__ bm2,    // (256, 768)
    const float* __restrict__ b1, const float* __restrict__ g1,
    const float* __restrict__ be1,
    const float* __restrict__ b2, const float* __restrict__ g2,
    const float* __restrict__ be2,
    const float* __restrict__ wl, const float* __restrict__ bl,
    float* __restrict__ pred)          // (B, T)
{
    __shared__ __align__(16) unsigned char ring[3 * BUFSZ];
    __shared__ __align__(16) __bf16 h1[H1ROWS * D_];   // 512B rows, swizzled
    __shared__ float part1[M1 * 4 * 2];
    __shared__ float tot1[M1 * 2];
    __shared__ float part2[TILE_M * 4 * 4];
    __shared__ float sg[2];

    const int tid = threadIdx.x, lane = tid & 63, wid = tid >> 6;
    const int p = lane & 15, q = lane >> 4;
    const int m0 = blockIdx.x * TILE_M;
    const int bb = m0 >> 9, t0 = m0 & 511;
    const int tb = t0 - 8;                      // conv1 row r <-> global t=tb+r
    const __bf16* xb = xpad + (size_t)bb * TP_ * D_;

    if (tid < 64) {   // Sgw = sum g2*wl, Sbw = sum be2*wl + bl
        f32x4 g  = *(const f32x4*)(g2  + 4 * tid);
        f32x4 be = *(const f32x4*)(be2 + 4 * tid);
        f32x4 w  = *(const f32x4*)(wl  + 4 * tid);
        float a = g[0]*w[0] + g[1]*w[1] + g[2]*w[2] + g[3]*w[3];
        float b = be[0]*w[0] + be[1]*w[1] + be[2]*w[2] + be[3]*w[3];
#pragma unroll
        for (int off = 32; off >= 1; off >>= 1) {
            a += __shfl_xor(a, off); b += __shfl_xor(b, off);
        }
        if (tid == 0) { sg[0] = a; sg[1] = b + bl[0]; }
    }

    // ============================ conv1 ====================================
    f32x4 acc1[5][4];
#pragma unroll
    for (int mf = 0; mf < 5; ++mf)
#pragma unroll
        for (int nf = 0; nf < 4; ++nf)
            acc1[mf][nf] = (f32x4){0.f, 0.f, 0.f, 0.f};

    auto STAGE1 = [&](int kstep, int buf) {
        unsigned char* Ab = ring + buf * BUFSZ;
        const int k = kstep >> 3, i0 = (kstep & 7) * 32;
        {   // A chunks 0..255 (rows 0..63)
            int c = tid, r = c >> 2, scb = (c & 3) ^ (r & 3);
            int idx = tb + r + k;
            idx = idx < 0 ? 0 : (idx > 513 ? 513 : idx);
            gload16(xb + (size_t)idx * D_ + i0 + scb * 8, Ab + c * 16);
        }
        if (wid == 0) {   // A chunks 256..319 (rows 64..79), lane-linear dest
            int c = 256 + lane, r = c >> 2, scb = (c & 3) ^ (r & 3);
            int idx = tb + r + k;
            idx = idx < 0 ? 0 : (idx > 513 ? 513 : idx);
            gload16(xb + (size_t)idx * D_ + i0 + scb * 8, Ab + c * 16);
        }
#pragma unroll
        for (int pp = 0; pp < 4; ++pp) {   // B1: 256 rows x 32 bf16
            int c = pp * 256 + tid;
            int n = c >> 2, scb = (c & 3) ^ (n & 3);
            gload16(bm1 + (size_t)n * KTOT + kstep * 32 + scb * 8,
                    Ab + 5120 + c * 16);
        }
    };
    auto COMPUTE1 = [&](int buf) {
        unsigned char* Ab = ring + buf * BUFSZ;
        unsigned char* Bb = Ab + 5120;
        const int swz = (q ^ (p & 3)) * 16;
        bf16x8 a[5], bv[4];
#pragma unroll
        for (int mf = 0; mf < 5; ++mf)
            a[mf] = *(const bf16x8*)(Ab + (mf * 16 + p) * 64 + swz);
#pragma unroll
        for (int nf = 0; nf < 4; ++nf)
            bv[nf] = *(const bf16x8*)(Bb + (wid * 64 + nf * 16 + p) * 64 + swz);
#pragma unroll
        for (int mf = 0; mf < 5; ++mf)
#pragma unroll
            for (int nf = 0; nf < 4; ++nf)
                acc1[mf][nf] = __builtin_amdgcn_mfma_f32_16x16x32_bf16(
                    a[mf], bv[nf], acc1[mf][nf], 0, 0, 0);
    };

    STAGE1(0, 0); STAGE1(1, 1);
#pragma unroll
    for (int k = 0; k < NSTEP; ++k) {
        if (k == NSTEP - 1)  asm volatile("s_waitcnt vmcnt(0)" ::: "memory");
        else if (wid == 0)   asm volatile("s_waitcnt vmcnt(6)" ::: "memory");
        else                 asm volatile("s_waitcnt vmcnt(5)" ::: "memory");
        __builtin_amdgcn_s_barrier();
        if (k + 2 < NSTEP) STAGE1(k + 2, (k + 2) % 3);
        COMPUTE1(k % 3);
    }

    // ---- conv1 epilogue: bias+ReLU partials -> LN stats ----
    float bcol[4], gcol[4], becol[4];
#pragma unroll
    for (int nf = 0; nf < 4; ++nf) {
        int c = wid * 64 + nf * 16 + p;
        bcol[nf] = b1[c]; gcol[nf] = g1[c]; becol[nf] = be1[c];
    }
#pragma unroll
    for (int mf = 0; mf < 5; ++mf)
#pragma unroll
        for (int r = 0; r < 4; ++r) {
            float s = 0.f, s2 = 0.f;
#pragma unroll
            for (int nf = 0; nf < 4; ++nf) {
                float y = fmaxf(acc1[mf][nf][r] + bcol[nf], 0.f);
                s += y; s2 += y * y;
            }
#pragma unroll
            for (int off = 8; off >= 1; off >>= 1) {
                s += __shfl_xor(s, off); s2 += __shfl_xor(s2, off);
            }
            if (p == 0) {
                int row = mf * 16 + q * 4 + r;
                part1[(row * 4 + wid) * 2]     = s;
                part1[(row * 4 + wid) * 2 + 1] = s2;
            }
        }
    __syncthreads();

    // prefetch conv2 B stages 0,1 under the LN tail (ring bufs 0,1 are free)
    auto STAGE2 = [&](int kstep, int buf) {
#pragma unroll
        for (int pp = 0; pp < 4; ++pp) {
            int c = pp * 256 + tid;
            int n = c >> 2, scb = (c & 3) ^ (n & 3);
            gload16(bm2 + (size_t)n * KTOT + kstep * 32 + scb * 8,
                    ring + buf * BUFSZ + c * 16);
        }
    };
    STAGE2(0, 0); STAGE2(1, 1);

    if (tid < M1) {
        float s = 0.f, s2 = 0.f;
#pragma unroll
        for (int w = 0; w < 4; ++w) {
            s  += part1[(tid * 4 + w) * 2];
            s2 += part1[(tid * 4 + w) * 2 + 1];
        }
        float m = s * (1.f / 256.f);
        float v = s2 * (1.f / 256.f) - m * m;
        tot1[tid * 2]     = m;
        tot1[tid * 2 + 1] = rsqrtf(v + 1e-5f);
    }
    __syncthreads();

    // ---- write LN'd h1 rows u=[0,66) to LDS (slot-XOR swizzle) ----
#pragma unroll
    for (int mf = 0; mf < 5; ++mf)
#pragma unroll
        for (int r = 0; r < 4; ++r) {
            int row = mf * 16 + q * 4 + r;     // 0..79
            int u = row - 7;                    // h1 index
            if (u >= 0 && u < H1ROWS) {
                float m  = tot1[row * 2];
                float rs = tot1[row * 2 + 1];
#pragma unroll
                for (int nf = 0; nf < 4; ++nf) {
                    int c = wid * 64 + nf * 16 + p;
                    float y = fmaxf(acc1[mf][nf][r] + bcol[nf], 0.f);
                    float val = (y - m) * rs * gcol[nf] + becol[nf];
                    int phys = (c >> 3) ^ (u & 7);
                    h1[u * D_ + phys * 8 + (c & 7)] = (__bf16)val;
                }
            }
        }
    // zero the OOB halo rows (t=-1 at u=0 for t0==0; t=512 at u=65 for t0==448)
    if (t0 == 0 && tid < 32)
        *(bf16x8*)(h1 + tid * 8) = (bf16x8){};
    if (t0 == 448 && tid < 32)
        *(bf16x8*)(h1 + 65 * D_ + tid * 8) = (bf16x8){};
    __syncthreads();

    // ============================ conv2 ====================================
    f32x4 acc2[4][4];
#pragma unroll
    for (int mf = 0; mf < 4; ++mf)
#pragma unroll
        for (int nf = 0; nf < 4; ++nf)
            acc2[mf][nf] = (f32x4){0.f, 0.f, 0.f, 0.f};

    auto COMPUTE2 = [&](int kstep) {
        unsigned char* Bb = ring + (kstep % 3) * BUFSZ;
        const int k2 = kstep >> 3;
        const int cs = (kstep & 7) * 4;        // col-slot base (32 cols/step)
        const int swz = (q ^ (p & 3)) * 16;
        bf16x8 a[4], bv[4];
#pragma unroll
        for (int mf = 0; mf < 4; ++mf) {
            int u = mf * 16 + p + k2;          // 0..65
            int phys = (cs + q) ^ (u & 7);
            a[mf] = *(const bf16x8*)(h1 + u * D_ + phys * 8);
        }
#pragma unroll
        for (int nf = 0; nf < 4; ++nf)
            bv[nf] = *(const bf16x8*)(Bb + (wid * 64 + nf * 16 + p) * 64 + swz);
#pragma unroll
        for (int mf = 0; mf < 4; ++mf)
#pragma unroll
            for (int nf = 0; nf < 4; ++nf)
                acc2[mf][nf] = __builtin_amdgcn_mfma_f32_16x16x32_bf16(
                    a[mf], bv[nf], acc2[mf][nf], 0, 0, 0);
    };

#pragma unroll
    for (int k = 0; k < NSTEP; ++k) {
        if (k == NSTEP - 1) asm volatile("s_waitcnt vmcnt(0)" ::: "memory");
        else                asm volatile("s_waitcnt vmcnt(4)" ::: "memory");
        __builtin_amdgcn_s_barrier();
        if (k + 2 < NSTEP) STAGE2(k + 2, (k + 2) % 3);
        COMPUTE2(k);
    }

    // ---- conv2 epilogue: fused LN + linear -> pred ----
    float bcol2[4], gwcol[4];
#pragma unroll
    for (int nf = 0; nf < 4; ++nf) {
        int c = wid * 64 + nf * 16 + p;
        bcol2[nf] = b2[c];
        gwcol[nf] = g2[c] * wl[c];
    }
#pragma unroll
    for (int mf = 0; mf < 4; ++mf)
#pragma unroll
        for (int r = 0; r < 4; ++r) {
            float s = 0.f, s2 = 0.f, s3 = 0.f;
#pragma unroll
            for (int nf = 0; nf < 4; ++nf) {
                float y = fmaxf(acc2[mf][nf][r] + bcol2[nf], 0.f);
                s += y; s2 += y * y; s3 += y * gwcol[nf];
            }
#pragma unroll
            for (int off = 8; off >= 1; off >>= 1) {
                s  += __shfl_xor(s, off);
                s2 += __shfl_xor(s2, off);
                s3 += __shfl_xor(s3, off);
            }
            if (p == 0) {
                int row = mf * 16 + q * 4 + r;
                part2[(row * 4 + wid) * 4]     = s;
                part2[(row * 4 + wid) * 4 + 1] = s2;
                part2[(row * 4 + wid) * 4 + 2] = s3;
            }
        }
    __syncthreads();
    if (tid < 64) {
        float s = 0.f, s2 = 0.f, s3 = 0.f;
#pragma unroll
        for (int w = 0; w < 4; ++w) {
            s  += part2[(tid * 4 + w) * 4];
            s2 += part2[(tid * 4 + w) * 4 + 1];
            s3 += part2[(tid * 4 + w) * 4 + 2];
        }
        float m  = s * (1.f / 256.f);
        float v  = s2 * (1.f / 256.f) - m * m;
        float rs = rsqrtf(v + 1e-5f);
        pred[bb * T_ + t0 + tid] = rs * (s3 - m * sg[0]) + sg[1];
    }
}

// prep: scan (blocks 0..31) + bf16 xpad + weight transpose.
__global__ __launch_bounds__(512) void prep_kernel(
    const int* __restrict__ td, const float* __restrict__ x,
    const float* __restrict__ w1, const float* __restrict__ w2,
    int* __restrict__ ends, __bf16* __restrict__ xpad,
    __bf16* __restrict__ bm1, __bf16* __restrict__ bm2)
{
    if (blockIdx.x < 32) {   // inclusive cumsum per batch
        __shared__ int s[T_];
        int b = blockIdx.x, t = threadIdx.x;
        s[t] = td[b * T_ + t];
        __syncthreads();
        for (int off = 1; off < T_; off <<= 1) {
            int add = (t >= off) ? s[t - off] : 0;
            __syncthreads();
            s[t] += add;
            __syncthreads();
        }
        ends[b * T_ + t] = s[t];
        return;
    }
    const int NX8 = B_ * TP_ * D_ / 8;   // 526,336
    const int NW8 = D_ * KTOT / 8;       // 24,576 per conv
    int idx = (blockIdx.x - 32) * 512 + threadIdx.x;
    if (idx < NX8) {
        int e = idx * 8;
        int b = e / (TP_ * D_);
        int rem = e - b * (TP_ * D_);
        int r = rem >> 8, d = rem & 255;
        int t = r - 1;
        bf16x8 o;
        if ((unsigned)t < (unsigned)T_) {
            const float* xp = x + ((size_t)b * T_ + t) * D_ + d;
            f32x4 v0 = *(const f32x4*)xp;
            f32x4 v1 = *(const f32x4*)(xp + 4);
#pragma unroll
            for (int u = 0; u < 4; ++u) { o[u] = (__bf16)v0[u]; o[u+4] = (__bf16)v1[u]; }
        } else {
#pragma unroll
            for (int u = 0; u < 8; ++u) o[u] = (__bf16)0.f;
        }
        *(bf16x8*)(xpad + e) = o;
    } else if (idx < NX8 + 2 * NW8) {
        int j = (idx - NX8) * 8;
        const float* ws = w1;
        __bf16* bm = bm1;
        if (j >= D_ * KTOT) { j -= D_ * KTOT; ws = w2; bm = bm2; }
        int n = j / KTOT;
        int kap = j - n * KTOT;
        int k = kap >> 8, i = kap & 255;
        bf16x8 o;
#pragma unroll
        for (int u = 0; u < 8; ++u)
            o[u] = (__bf16)ws[(n * D_ + i + u) * 3 + k];
        *(bf16x8*)(bm + n * KTOT + kap) = o;
    }
}

// out[b,m,:] = x[b, t(m), :] via binary search over ends; zeros past lens[b].
__global__ __launch_bounds__(256) void gather_kernel(
    const float* __restrict__ x, const int* __restrict__ ends,
    float* __restrict__ out, int maxLen)
{
    int tid = threadIdx.x, wd = tid >> 6, lane = tid & 63;
    int idx = blockIdx.x * 4 + wd;
    int b = idx / maxLen, m = idx % maxLen;
    if (b >= B_) return;
    const int* e = &ends[b * T_];
    float4 r = make_float4(0.f, 0.f, 0.f, 0.f);
    if (m < e[T_ - 1]) {
        int lo = 0, hi = T_ - 1;   // first t with ends[t] > m
        while (lo < hi) {
            int mid = (lo + hi) >> 1;
            if (e[mid] > m) hi = mid; else lo = mid + 1;
        }
        r = *(const float4*)(&x[((size_t)b * T_ + lo) * D_ + 4 * lane]);
    }
    *(float4*)(&out[((size_t)b * maxLen + m) * D_ + 4 * lane]) = r;
}

extern "C" void kernel_launch(void* const* d_in, const int* in_sizes, int n_in,
                              void* d_out, int out_size, void* d_ws, size_t ws_size,
                              hipStream_t stream) {
    const float* x   = (const float*)d_in[0];
    const int*   td  = (const int*)d_in[1];
    const float* w1  = (const float*)d_in[2];
    const float* b1  = (const float*)d_in[3];
    const float* g1  = (const float*)d_in[4];
    const float* be1 = (const float*)d_in[5];
    const float* w2  = (const float*)d_in[6];
    const float* b2  = (const float*)d_in[7];
    const float* g2  = (const float*)d_in[8];
    const float* be2 = (const float*)d_in[9];
    const float* wl  = (const float*)d_in[10];
    const float* bl  = (const float*)d_in[11];
    float* outp = (float*)d_out;

    const int BT = B_ * T_;
    const int maxLen = (out_size - BT) / (B_ * D_);
    float* predp = outp + (size_t)B_ * maxLen * D_;

    const size_t SZ_ENDS = 65536;
    const size_t SZ_XPAD = (size_t)B_ * TP_ * D_ * 2;   // 8,421,376
    const size_t SZ_BM   = (size_t)D_ * KTOT * 2;       // 393,216
    const size_t need = SZ_ENDS + SZ_XPAD + 2 * SZ_BM;

    int* endsp = (int*)d_ws;                             // always in ws (tiny)
    char* base;
    if (ws_size >= need) base = (char*)d_ws + SZ_ENDS;
    else                 base = (char*)d_out;  // consumed before gather overwrites

    __bf16* xpadp = (__bf16*)(base);
    __bf16* bm1p  = (__bf16*)(base + SZ_XPAD);
    __bf16* bm2p  = (__bf16*)(base + SZ_XPAD + SZ_BM);

    const int NX8 = B_ * TP_ * D_ / 8, NW8 = D_ * KTOT / 8;
    const int prepBlocks = 32 + (NX8 + 2 * NW8 + 511) / 512;

    prep_kernel<<<prepBlocks, 512, 0, stream>>>(td, x, w1, w2, endsp, xpadp,
                                                bm1p, bm2p);
    fused_conv_kernel<<<BT / TILE_M, 256, 0, stream>>>(
        xpadp, bm1p, bm2p, b1, g1, be1, b2, g2, be2, wl, bl, predp);
    gather_kernel<<<(B_ * maxLen + 3) / 4, 256, 0, stream>>>(x, endsp, outp, maxLen);
}